// Round 1
// baseline (580.783 us; speedup 1.0000x reference)
//
#include <hip/hip_runtime.h>
#include <hip/hip_bf16.h>
#include <utility>

#define DEV __device__ __forceinline__

constexpr int BATCH = 16384;
constexpr int T = 64;
constexpr int H = 14;

// ---- compile-time unroll helper (ds_swizzle needs an ICE pattern) ----
template <class F, int... Is>
DEV void unroll_impl(F&& f, std::integer_sequence<int, Is...>) {
  (f(std::integral_constant<int, Is>{}), ...);
}
template <int N, class F>
DEV void unroll(F&& f) {
  unroll_impl(static_cast<F&&>(f), std::make_integer_sequence<int, N>{});
}

DEV float fast_sig(float x) {
  // 1/(1+exp(-x)); exp(-x) = 2^(-x*log2 e). Large +arg -> rcp(inf)=0: safe.
  float e = __builtin_amdgcn_exp2f(x * -1.442695041f);
  return __builtin_amdgcn_rcpf(1.0f + e);
}
DEV float fast_tanh(float x) {
  // tanh on |x| then copysign: avoids inf/inf NaN for very negative args.
  float a = fabsf(x);
  float e = __builtin_amdgcn_exp2f(a * -2.885390082f);  // exp(-2a)
  float t = (1.0f - e) * __builtin_amdgcn_rcpf(1.0f + e);
  return copysignf(t, x);
}

// One LSTM layer (one direction per blockIdx.y). 16 lanes per sequence,
// lane j in [0,14) owns hidden index j (gate rows j, 14+j, 28+j, 42+j).
// Weights held in VGPRs; h broadcast within the 16-lane group via ds_swizzle.
template <int IN>
__global__ __launch_bounds__(256, 2) void lstm_fwd(
    const float* __restrict__ x,      // [B, T, IN]
    const float* __restrict__ wihF, const float* __restrict__ whhF,
    const float* __restrict__ bihF, const float* __restrict__ bhhF,
    const float* __restrict__ wihB, const float* __restrict__ whhB,
    const float* __restrict__ bihB, const float* __restrict__ bhhB,
    float* __restrict__ y,            // [B, T, OC]
    int OC) {
  const int dir = blockIdx.y;
  const float* __restrict__ wih = dir ? wihB : wihF;
  const float* __restrict__ whh = dir ? whhB : whhF;
  const float* __restrict__ bih = dir ? bihB : bihF;
  const float* __restrict__ bhh = dir ? bhhB : bhhF;

  const int tid = threadIdx.x;
  const int grp = tid >> 4;          // sequence within block (0..15)
  const int j   = tid & 15;          // hidden index; 14,15 are idle clones
  const int jj  = j < 14 ? j : 13;   // clamp for weight loads
  const long seq = (long)blockIdx.x * 16 + grp;
  const int oco = dir * H;           // output channel offset

  // ---- per-thread weights into registers (once; amortized over T=64) ----
  float wi[4][IN], wh[4][H], bb[4];
#pragma unroll
  for (int g = 0; g < 4; ++g) {
    const int row = g * H + jj;
#pragma unroll
    for (int k = 0; k < IN; ++k) wi[g][k] = wih[row * IN + k];
#pragma unroll
    for (int k = 0; k < H; ++k) wh[g][k] = whh[row * H + k];
    bb[g] = bih[row] + bhh[row];
  }

  const float* __restrict__ xb = x + seq * (long)T * IN;
  float hv = 0.0f, cv = 0.0f;

  for (int s = 0; s < T; ++s) {
    const int t = dir ? (T - 1 - s) : s;
    const float* __restrict__ xr = xb + t * IN;

    float z0 = bb[0], z1 = bb[1], z2 = bb[2], z3 = bb[3];

    // x contribution (broadcast loads: same address across the 16-lane group)
    if constexpr (IN == 28) {
      // rows are 112B -> 16B aligned; float4 loads
#pragma unroll
      for (int q = 0; q < 7; ++q) {
        const float4 xv = reinterpret_cast<const float4*>(xr)[q];
        z0 += wi[0][4 * q + 0] * xv.x; z1 += wi[1][4 * q + 0] * xv.x;
        z2 += wi[2][4 * q + 0] * xv.x; z3 += wi[3][4 * q + 0] * xv.x;
        z0 += wi[0][4 * q + 1] * xv.y; z1 += wi[1][4 * q + 1] * xv.y;
        z2 += wi[2][4 * q + 1] * xv.y; z3 += wi[3][4 * q + 1] * xv.y;
        z0 += wi[0][4 * q + 2] * xv.z; z1 += wi[1][4 * q + 2] * xv.z;
        z2 += wi[2][4 * q + 2] * xv.z; z3 += wi[3][4 * q + 2] * xv.z;
        z0 += wi[0][4 * q + 3] * xv.w; z1 += wi[1][4 * q + 3] * xv.w;
        z2 += wi[2][4 * q + 3] * xv.w; z3 += wi[3][4 * q + 3] * xv.w;
      }
    } else {
#pragma unroll
      for (int k = 0; k < IN; ++k) {
        const float xv = xr[k];
        z0 += wi[0][k] * xv; z1 += wi[1][k] * xv;
        z2 += wi[2][k] * xv; z3 += wi[3][k] * xv;
      }
    }

    // h contribution: broadcast h_k from lane k of this 16-lane group.
    // ds_swizzle BitMode: src = (lane & 0x10) | k  (within 32-lane half)
    const unsigned hb = __float_as_uint(hv);
    unroll<H>([&](auto kc) {
      constexpr int k = decltype(kc)::value;
      const float hk =
          __uint_as_float(__builtin_amdgcn_ds_swizzle((int)hb, (k << 5) | 0x10));
      z0 += wh[0][k] * hk; z1 += wh[1][k] * hk;
      z2 += wh[2][k] * hk; z3 += wh[3][k] * hk;
    });

    const float ig = fast_sig(z0);
    const float fg = fast_sig(z1);
    const float gg = fast_tanh(z2);
    const float og = fast_sig(z3);
    cv = fg * cv + ig * gg;
    hv = og * fast_tanh(cv);

    if (j < H) y[(seq * (long)T + t) * OC + oco + j] = hv;
  }
}

extern "C" void kernel_launch(void* const* d_in, const int* in_sizes, int n_in,
                              void* d_out, int out_size, void* d_ws, size_t ws_size,
                              hipStream_t stream) {
  const float* x     = (const float*)d_in[0];
  const float* wih1f = (const float*)d_in[1];
  const float* whh1f = (const float*)d_in[2];
  const float* bih1f = (const float*)d_in[3];
  const float* bhh1f = (const float*)d_in[4];
  const float* wih1b = (const float*)d_in[5];
  const float* whh1b = (const float*)d_in[6];
  const float* bih1b = (const float*)d_in[7];
  const float* bhh1b = (const float*)d_in[8];
  const float* wih2f = (const float*)d_in[9];
  const float* whh2f = (const float*)d_in[10];
  const float* bih2f = (const float*)d_in[11];
  const float* bhh2f = (const float*)d_in[12];
  const float* wih2b = (const float*)d_in[13];
  const float* whh2b = (const float*)d_in[14];
  const float* bih2b = (const float*)d_in[15];
  const float* bhh2b = (const float*)d_in[16];
  const float* wih3  = (const float*)d_in[17];
  const float* whh3  = (const float*)d_in[18];
  const float* bih3  = (const float*)d_in[19];
  const float* bhh3  = (const float*)d_in[20];

  float* y1 = (float*)d_ws;                          // [B, T, 28]
  float* y2 = y1 + (size_t)BATCH * T * 2 * H;        // [B, T, 28]
  float* out = (float*)d_out;                        // [B, T, 14]

  const dim3 blk(256);
  const dim3 grid_bi(BATCH / 16, 2);
  const dim3 grid_uni(BATCH / 16, 1);

  // layer 1: bidirectional, in=13
  lstm_fwd<13><<<grid_bi, blk, 0, stream>>>(
      x, wih1f, whh1f, bih1f, bhh1f, wih1b, whh1b, bih1b, bhh1b, y1, 2 * H);
  // layer 2: bidirectional, in=28
  lstm_fwd<28><<<grid_bi, blk, 0, stream>>>(
      y1, wih2f, whh2f, bih2f, bhh2f, wih2b, whh2b, bih2b, bhh2b, y2, 2 * H);
  // layer 3: unidirectional, in=28
  lstm_fwd<28><<<grid_uni, blk, 0, stream>>>(
      y2, wih3, whh3, bih3, bhh3, wih3, whh3, bih3, bhh3, out, H);
}

// Round 2
// 398.187 us; speedup vs baseline: 1.4586x; 1.4586x over previous
//
#include <hip/hip_runtime.h>
#include <hip/hip_bf16.h>

#define DEV __device__ __forceinline__

typedef short bf16x8 __attribute__((ext_vector_type(8)));
typedef float f32x4 __attribute__((ext_vector_type(4)));

constexpr int BATCH = 16384;
constexpr int T = 64;
constexpr int H = 14;

// bf16 round-to-nearest-even on raw bits (finite values only)
DEV unsigned bf_rne(float x) {
  unsigned u = __float_as_uint(x);
  return (u + 0x7FFFu + ((u >> 16) & 1u)) >> 16;
}
DEV float bf_back(unsigned b) { return __uint_as_float(b << 16); }

struct S3 { unsigned b1, b2, b3; };
DEV S3 split3(float x) {
  S3 s;
  s.b1 = bf_rne(x);
  float r1 = x - bf_back(s.b1);
  s.b2 = bf_rne(r1);
  s.b3 = bf_rne(r1 - bf_back(s.b2));
  return s;
}

union Frag {
  bf16x8 v;
  unsigned u[4];
};

DEV float fast_sig(float x) {
  float e = __builtin_amdgcn_exp2f(x * -1.442695041f);
  return __builtin_amdgcn_rcpf(1.0f + e);
}
DEV float fast_tanh(float x) {
  float a = fabsf(x);
  float e = __builtin_amdgcn_exp2f(a * -2.885390082f);
  float t = (1.0f - e) * __builtin_amdgcn_rcpf(1.0f + e);
  return copysignf(t, x);
}

DEV f32x4 MFMA(Frag a, Frag b, f32x4 c) {
  return __builtin_amdgcn_mfma_f32_16x16x32_bf16(a.v, b.v, c, 0, 0, 0);
}

// One LSTM layer, one direction per blockIdx.y. One wave handles 16 sequences
// via 16x16x32 bf16 MFMA on padded gate-rows (4 gates x 16 rows = 4 N-tiles).
// fp32-equivalent precision via 3-way bf16 splits (6 cross-products).
// A-frag row = seq (lane&15), k = 8*(lane>>4)+e. B-frag col = gate-row j
// (lane&15), same k layout. C: col = lane&15, row(seq) = 4*(lane>>4)+reg.
template <int IN, bool PACKX>
__global__ __launch_bounds__(256, 2) void lstm_mfma(
    const float* __restrict__ x,
    const float* __restrict__ wihF, const float* __restrict__ whhF,
    const float* __restrict__ bihF, const float* __restrict__ bhhF,
    const float* __restrict__ wihB, const float* __restrict__ whhB,
    const float* __restrict__ bihB, const float* __restrict__ bhhB,
    float* __restrict__ y, int OC) {
  const int dir = blockIdx.y;
  const float* __restrict__ wih = dir ? wihB : wihF;
  const float* __restrict__ whh = dir ? whhB : whhF;
  const float* __restrict__ bih = dir ? bihB : bihF;
  const float* __restrict__ bhh = dir ? bhhB : bhhF;
  const int oco = dir * H;

  const int tid = threadIdx.x;
  const int w = tid >> 6;
  const int lane = tid & 63;
  const int col = lane & 15;  // B/C column (gate-row j) AND A row (seq)
  const int q = lane >> 4;
  const bool jv = col < H;

  __shared__ float hbuf[4][16][15];  // [wave][seq][j] (stride 15: no conflicts)
  {
    float* hb = &hbuf[w][0][0];
    for (int i = lane; i < 240; i += 64) hb[i] = 0.0f;
  }

  // ---------------- weight fragments (built once) ----------------
  Frag BX1[4], BX2[4], BX3[4];  // x-part  (solo: W1,W2,W3 ; packed: [W1|W1],[W2|W2],[W3|W1])
  Frag BH1[4], BH2[4], BH3[4];  // h-part  [W1|W1],[W2|W2],[W3|W1] over KH=14
  float bb[4];
#pragma unroll
  for (int g = 0; g < 4; ++g) {
    const int row = g * H + (jv ? col : 0);
#pragma unroll
    for (int p = 0; p < 4; ++p) {
      unsigned ux1 = 0, ux2 = 0, ux3 = 0, uh1 = 0, uh2 = 0, uh3 = 0;
#pragma unroll
      for (int half_ = 0; half_ < 2; ++half_) {
        const int e = 2 * p + half_;
        const int k = 8 * q + e;
        {  // x weights
          unsigned e1 = 0, e2 = 0, e3 = 0;
          if (PACKX) {
            const bool lo = k < IN;
            const bool hi2 = (k >= IN) && (k < 2 * IN);
            const int kk = lo ? k : (hi2 ? k - IN : 0);
            const float wv = (jv && (lo || hi2)) ? wih[row * IN + kk] : 0.0f;
            S3 s = split3(wv);
            e1 = (lo || hi2) ? s.b1 : 0;
            e2 = (lo || hi2) ? s.b2 : 0;
            e3 = lo ? s.b3 : (hi2 ? s.b1 : 0);
          } else {
            const float wv = (jv && k < IN) ? wih[row * IN + k] : 0.0f;
            S3 s = split3(wv);
            e1 = s.b1; e2 = s.b2; e3 = s.b3;
          }
          ux1 |= e1 << (16 * half_); ux2 |= e2 << (16 * half_); ux3 |= e3 << (16 * half_);
        }
        {  // h weights
          const bool lo = k < H;
          const bool hi2 = (k >= H) && (k < 2 * H);
          const int kk = lo ? k : (hi2 ? k - H : 0);
          const float wv = (jv && (lo || hi2)) ? whh[row * H + kk] : 0.0f;
          S3 s = split3(wv);
          const unsigned f1 = (lo || hi2) ? s.b1 : 0;
          const unsigned f2 = (lo || hi2) ? s.b2 : 0;
          const unsigned f3 = lo ? s.b3 : (hi2 ? s.b1 : 0);
          uh1 |= f1 << (16 * half_); uh2 |= f2 << (16 * half_); uh3 |= f3 << (16 * half_);
        }
      }
      BX1[g].u[p] = ux1; BX2[g].u[p] = ux2; BX3[g].u[p] = ux3;
      BH1[g].u[p] = uh1; BH2[g].u[p] = uh2; BH3[g].u[p] = uh3;
    }
    bb[g] = jv ? (bih[row] + bhh[row]) : 0.0f;
  }

  const long sb = (long)blockIdx.x * 64 + (long)w * 16;  // wave's first seq
  const long arow = sb + col;                            // A-frag row = seq
  const float* __restrict__ xbase = x + (long)arow * T * IN;

  float c0 = 0.f, c1 = 0.f, c2 = 0.f, c3 = 0.f;

  float xA[8], xB[8];
  auto loadx = [&](float (&dst)[8], int t) {
    const float* __restrict__ xr = xbase + t * IN;
#pragma unroll
    for (int e = 0; e < 8; ++e) {
      const int k = 8 * q + e;
      const int lim = PACKX ? 2 * IN : IN;
      const int kk = (k < IN) ? k : ((PACKX && k < 2 * IN) ? k - IN : 0);
      dst[e] = (k < lim) ? xr[kk] : 0.0f;
    }
  };

  auto step = [&](int t, int tn, float (&xc)[8], float (&xn)[8]) {
    // 1. prefetch next x (consumed next step)
    loadx(xn, tn);
    // 2. x A-frags
    Frag Ax1, Ax2, Ax3;  // solo: comp1/2/3 ; packed: A12=[x1|x2], A13=[x1|x3]
#pragma unroll
    for (int p = 0; p < 4; ++p) {
      unsigned u1 = 0, u2 = 0, u3 = 0;
#pragma unroll
      for (int half_ = 0; half_ < 2; ++half_) {
        const int e = 2 * p + half_;
        const int k = 8 * q + e;
        S3 s = split3(xc[e]);
        unsigned e1, e2, e3;
        if (PACKX) {
          e1 = (k < IN) ? s.b1 : s.b2;
          e2 = (k < IN) ? s.b1 : s.b3;
          e3 = 0;
        } else {
          e1 = s.b1; e2 = s.b2; e3 = s.b3;
        }
        u1 |= e1 << (16 * half_); u2 |= e2 << (16 * half_); u3 |= e3 << (16 * half_);
      }
      Ax1.u[p] = u1; Ax2.u[p] = u2; Ax3.u[p] = u3;
    }
    // 3. h A-frags from LDS (written by this wave last step)
    Frag Ah12, Ah13;
#pragma unroll
    for (int p = 0; p < 4; ++p) {
      unsigned u1 = 0, u2 = 0;
#pragma unroll
      for (int half_ = 0; half_ < 2; ++half_) {
        const int e = 2 * p + half_;
        const int k = 8 * q + e;
        const int jh = (k < H) ? k : ((k < 2 * H) ? k - H : 0);
        const float hv = (k < 2 * H) ? hbuf[w][col][jh] : 0.0f;
        S3 s = split3(hv);
        const unsigned e1 = (k < H) ? s.b1 : s.b2;
        const unsigned e2 = (k < H) ? s.b1 : s.b3;
        u1 |= e1 << (16 * half_); u2 |= e2 << (16 * half_);
      }
      Ah12.u[p] = u1; Ah13.u[p] = u2;
    }
    // 4. MFMAs: z = bias + x·Wih^T + h·Whh^T (3-way split products)
    f32x4 acc[4];
#pragma unroll
    for (int g = 0; g < 4; ++g) {
      f32x4 a = {bb[g], bb[g], bb[g], bb[g]};
      if (PACKX) {
        a = MFMA(Ax1, BX1[g], a);  // x1W1 + x2W1
        a = MFMA(Ax1, BX2[g], a);  // x1W2 + x2W2
        a = MFMA(Ax2, BX3[g], a);  // x1W3 + x3W1
      } else {
        a = MFMA(Ax1, BX1[g], a);  // x1W1
        a = MFMA(Ax2, BX1[g], a);  // x2W1
        a = MFMA(Ax1, BX2[g], a);  // x1W2
        a = MFMA(Ax2, BX2[g], a);  // x2W2
        a = MFMA(Ax1, BX3[g], a);  // x1W3
        a = MFMA(Ax3, BX1[g], a);  // x3W1
      }
      a = MFMA(Ah12, BH1[g], a);  // h1W1 + h2W1
      a = MFMA(Ah12, BH2[g], a);  // h1W2 + h2W2
      a = MFMA(Ah13, BH3[g], a);  // h1W3 + h3W1
      acc[g] = a;
    }
    // 5. activations + cell update + stores
    float cc[4] = {c0, c1, c2, c3};
#pragma unroll
    for (int i = 0; i < 4; ++i) {
      const float zi = acc[0][i], zf = acc[1][i], zg = acc[2][i], zo = acc[3][i];
      const float cn = fast_sig(zf) * cc[i] + fast_sig(zi) * fast_tanh(zg);
      cc[i] = cn;
      const float hn = fast_sig(zo) * fast_tanh(cn);
      if (jv) {
        const long sg = sb + 4 * q + i;
        y[((long)sg * T + t) * OC + oco + col] = hn;
        hbuf[w][4 * q + i][col] = hn;
      }
    }
    c0 = cc[0]; c1 = cc[1]; c2 = cc[2]; c3 = cc[3];
  };

  const int t0 = dir ? T - 1 : 0;
  loadx(xA, t0);
#pragma unroll 1
  for (int s = 0; s < T; s += 2) {
    const int ta = dir ? T - 1 - s : s;
    const int tb = dir ? T - 2 - s : s + 1;
    const int tc = (s + 2 < T) ? (dir ? T - 3 - s : s + 2) : tb;
    step(ta, tb, xA, xB);
    step(tb, tc, xB, xA);
  }
}

extern "C" void kernel_launch(void* const* d_in, const int* in_sizes, int n_in,
                              void* d_out, int out_size, void* d_ws, size_t ws_size,
                              hipStream_t stream) {
  const float* x     = (const float*)d_in[0];
  const float* wih1f = (const float*)d_in[1];
  const float* whh1f = (const float*)d_in[2];
  const float* bih1f = (const float*)d_in[3];
  const float* bhh1f = (const float*)d_in[4];
  const float* wih1b = (const float*)d_in[5];
  const float* whh1b = (const float*)d_in[6];
  const float* bih1b = (const float*)d_in[7];
  const float* bhh1b = (const float*)d_in[8];
  const float* wih2f = (const float*)d_in[9];
  const float* whh2f = (const float*)d_in[10];
  const float* bih2f = (const float*)d_in[11];
  const float* bhh2f = (const float*)d_in[12];
  const float* wih2b = (const float*)d_in[13];
  const float* whh2b = (const float*)d_in[14];
  const float* bih2b = (const float*)d_in[15];
  const float* bhh2b = (const float*)d_in[16];
  const float* wih3  = (const float*)d_in[17];
  const float* whh3  = (const float*)d_in[18];
  const float* bih3  = (const float*)d_in[19];
  const float* bhh3  = (const float*)d_in[20];

  float* y1 = (float*)d_ws;                    // [B, T, 28]
  float* y2 = y1 + (size_t)BATCH * T * 2 * H;  // [B, T, 28]
  float* out = (float*)d_out;                  // [B, T, 14]

  const dim3 blk(256);
  const dim3 grid_bi(BATCH / 64, 2);
  const dim3 grid_uni(BATCH / 64, 1);

  lstm_mfma<13, true><<<grid_bi, blk, 0, stream>>>(
      x, wih1f, whh1f, bih1f, bhh1f, wih1b, whh1b, bih1b, bhh1b, y1, 2 * H);
  lstm_mfma<28, false><<<grid_bi, blk, 0, stream>>>(
      y1, wih2f, whh2f, bih2f, bhh2f, wih2b, whh2b, bih2b, bhh2b, y2, 2 * H);
  lstm_mfma<28, false><<<grid_uni, blk, 0, stream>>>(
      y2, wih3, whh3, bih3, bhh3, wih3, whh3, bih3, bhh3, out, H);
}

// Round 3
// 350.331 us; speedup vs baseline: 1.6578x; 1.1366x over previous
//
#include <hip/hip_runtime.h>
#include <hip/hip_bf16.h>

#define DEV __device__ __forceinline__

typedef short bf16x8 __attribute__((ext_vector_type(8)));
typedef float f32x4 __attribute__((ext_vector_type(4)));

constexpr int BATCH = 16384;
constexpr int T = 64;
constexpr int H = 14;
constexpr float NL2E = -1.4426950408889634f;   // -log2(e)
constexpr float N2L2E = -2.8853900817779268f;  // -2*log2(e)

DEV unsigned bf_rne(float x) {
  unsigned u = __float_as_uint(x);
  return (u + 0x7FFFu + ((u >> 16) & 1u)) >> 16;
}
DEV float bf_back(unsigned b) { return __uint_as_float(b << 16); }
// component c (1,2,3) of the 3-way bf16 split of w
DEV unsigned wcomp(float w, int c) {
  unsigned b1 = bf_rne(w);
  if (c == 1) return b1;
  float r1 = w - bf_back(b1);
  unsigned b2 = bf_rne(r1);
  if (c == 2) return b2;
  return bf_rne(r1 - bf_back(b2));
}

union Frag { bf16x8 v; unsigned u[4]; };

DEV unsigned cvtpk(float lo, float hi) {
  unsigned r;
  asm("v_cvt_pk_bf16_f32 %0, %1, %2" : "=v"(r) : "v"(lo), "v"(hi));
  return r;
}
DEV float pklo(unsigned u) { return __uint_as_float(u << 16); }
DEV float pkhi(unsigned u) { return __uint_as_float(u & 0xffff0000u); }

DEV f32x4 MFMA(Frag a, Frag b, f32x4 c) {
  return __builtin_amdgcn_mfma_f32_16x16x32_bf16(a.v, b.v, c, 0, 0, 0);
}

// One LSTM layer, one direction per blockIdx.y. Wave = 16 seqs.
// fp32-equivalent via 3-way bf16 splits; packing via v_cvt_pk_bf16_f32 with
// a section-permuted k-layout (A and B use the same permutation, so the dot
// product is unchanged). Physical k slot (d = 4*q+p, s) holds value pair
// (2d, 2d+1) of the section's component. Zero/garbage slots are killed by
// zeros in B. Bias rides in h-section slots k=14,15 with A=1.0 (LDS pads).
template <int IN, int OCP>  // IN: 13 (packed [x1|x2],[x1|x3]) or 28 (solo); OCP: y row stride
__global__ __launch_bounds__(256, 2) void lstm3(
    const float* __restrict__ x,
    const float* __restrict__ wihF, const float* __restrict__ whhF,
    const float* __restrict__ bihF, const float* __restrict__ bhhF,
    const float* __restrict__ wihB, const float* __restrict__ whhB,
    const float* __restrict__ bihB, const float* __restrict__ bhhB,
    float* __restrict__ y) {
  const int dir = blockIdx.y;
  const float* __restrict__ wih = dir ? wihB : wihF;
  const float* __restrict__ whh = dir ? whhB : whhF;
  const float* __restrict__ bih = dir ? bihB : bihF;
  const float* __restrict__ bhh = dir ? bhhB : bhhF;
  const int oco = dir * H;

  const int tid = threadIdx.x;
  const int w = tid >> 6, lane = tid & 63;
  const int col = lane & 15, q = lane >> 4;
  const bool jv = col < H;
  const bool qlo = q < 2;
  const int jc = jv ? col : 13;

  // h state per wave: [seq][20] floats; floats 14,15 fixed at 1.0 (bias A-slots)
  __shared__ __align__(16) float hbuf[4][16][20];
  {
    float* hb = &hbuf[w][0][0];
    for (int i = lane; i < 320; i += 64) {
      const int m = i % 20;
      hb[i] = (m == 14 || m == 15) ? 1.0f : 0.0f;
    }
  }

  // ---------------- B fragments (built once) ----------------
  Frag BX1[4], BX2[4], BX3[4], BH1[4], BH2[4], BH3[4];
#pragma unroll
  for (int g = 0; g < 4; ++g) {
    const int row = g * H + jc;
    const float* __restrict__ wr = wih + row * IN;
    const float* __restrict__ hr = whh + row * H;
    const float bsum = bih[row] + bhh[row];
#pragma unroll
    for (int p = 0; p < 4; ++p) {
      const int d = 4 * q + p;
      unsigned x1 = 0, x2 = 0, x3 = 0, h1 = 0, h2 = 0, h3 = 0;
#pragma unroll
      for (int s = 0; s < 2; ++s) {
        const int sh = 16 * s;
        // ---- x weights ----
        if (IN == 28) {
          const int k = 2 * d + s;
          if (jv && k < 28) {
            const float wv = wr[k];
            x1 |= wcomp(wv, 1) << sh; x2 |= wcomp(wv, 2) << sh; x3 |= wcomp(wv, 3) << sh;
          }
        } else {  // packed: BX1=[W1|W1], BX2=[W2|W2], BX3=[W3|W1]
          if (d < 8) {
            const int k = 2 * d + s;
            if (jv && k < 13) {
              const float wv = wr[k];
              x1 |= wcomp(wv, 1) << sh; x2 |= wcomp(wv, 2) << sh; x3 |= wcomp(wv, 3) << sh;
            }
          } else {
            const int k = 2 * (d - 8) + s;
            if (jv && k < 13) {
              const float wv = wr[k];
              x1 |= wcomp(wv, 1) << sh; x2 |= wcomp(wv, 2) << sh; x3 |= wcomp(wv, 1) << sh;
            }
          }
        }
        // ---- h weights: BH1=[W1|W1], BH2=[W2|W2], BH3=[W3|W1]; bias at d==7 ----
        if (d < 8) {
          const int k = 2 * d + s;
          if (jv && k < 14) {
            const float wv = hr[k];
            h1 |= wcomp(wv, 1) << sh; h2 |= wcomp(wv, 2) << sh; h3 |= wcomp(wv, 3) << sh;
          }
          if (d == 7 && jv) {  // k = 14,15 : A-side is 1.0
            h1 |= ((s == 0) ? wcomp(bsum, 1) : wcomp(bsum, 2)) << sh;
            if (s == 0) h2 |= wcomp(bsum, 3);
          }
        } else {
          const int k = 2 * (d - 8) + s;
          if (jv && k < 14) {
            const float wv = hr[k];
            h1 |= wcomp(wv, 1) << sh; h2 |= wcomp(wv, 2) << sh; h3 |= wcomp(wv, 1) << sh;
          }
        }
      }
      BX1[g].u[p] = x1; BX2[g].u[p] = x2; BX3[g].u[p] = x3;
      BH1[g].u[p] = h1; BH2[g].u[p] = h2; BH3[g].u[p] = h3;
    }
  }

  const long sb = (long)blockIdx.x * 64 + (long)w * 16;
  const long arow = sb + col;  // this lane's seq (A-frag row)
  const float* __restrict__ xrow = x + arow * (long)T * IN;

  // L1: clamped scalar offsets (row is 13 floats, 4B aligned only)
  int xo[8];
#pragma unroll
  for (int e = 0; e < 8; ++e) { int v = (q & 1) * 8 + e; xo[e] = v < 12 ? v : 12; }
  // L2/L3: two float4 loads; q==3's second load is dead (B=0) -> clamp in-row
  const int xo0 = q * 8;
  const int xo1 = (q == 3) ? 16 : q * 8 + 4;

  const float* __restrict__ hrow = &hbuf[w][col][(q & 1) * 8];

  float cc0 = 0.f, cc1 = 0.f, cc2 = 0.f, cc3 = 0.f;

  long yb[4];
#pragma unroll
  for (int i = 0; i < 4; ++i) yb[i] = (sb + 4 * q + i) * (long)T * OCP + oco + col;

  struct XB { float v[8]; };
  auto loadx = [&](XB& b, int t) {
    if (IN == 13) {
      const float* __restrict__ xr = xrow + t * 13;
#pragma unroll
      for (int e = 0; e < 8; ++e) b.v[e] = xr[xo[e]];
    } else {
      const float* __restrict__ xr = xrow + t * 28;
      const float4 a0 = *(const float4*)(xr + xo0);
      const float4 a1 = *(const float4*)(xr + xo1);
      b.v[0] = a0.x; b.v[1] = a0.y; b.v[2] = a0.z; b.v[3] = a0.w;
      b.v[4] = a1.x; b.v[5] = a1.y; b.v[6] = a1.z; b.v[7] = a1.w;
    }
  };

  auto split8 = [&](const float (&v)[8], unsigned (&P1)[4], unsigned (&P2)[4],
                    unsigned (&P3)[4]) {
    float r1[8], r2[8];
#pragma unroll
    for (int p = 0; p < 4; ++p) P1[p] = cvtpk(v[2 * p], v[2 * p + 1]);
#pragma unroll
    for (int p = 0; p < 4; ++p) {
      r1[2 * p] = v[2 * p] - pklo(P1[p]);
      r1[2 * p + 1] = v[2 * p + 1] - pkhi(P1[p]);
    }
#pragma unroll
    for (int p = 0; p < 4; ++p) P2[p] = cvtpk(r1[2 * p], r1[2 * p + 1]);
#pragma unroll
    for (int p = 0; p < 4; ++p) {
      r2[2 * p] = r1[2 * p] - pklo(P2[p]);
      r2[2 * p + 1] = r1[2 * p + 1] - pkhi(P2[p]);
    }
#pragma unroll
    for (int p = 0; p < 4; ++p) P3[p] = cvtpk(r2[2 * p], r2[2 * p + 1]);
  };

  auto step = [&](int t, int tn, XB& cur, XB& nxt) {
    loadx(nxt, tn);  // prefetch next step's x
    // ---- h fragments (from LDS, written last step by this wave) ----
    float hv[8];
    {
      const float4 a = *(const float4*)(hrow);
      const float4 b = *(const float4*)(hrow + 4);
      hv[0] = a.x; hv[1] = a.y; hv[2] = a.z; hv[3] = a.w;
      hv[4] = b.x; hv[5] = b.y; hv[6] = b.z; hv[7] = b.w;
    }
    unsigned HP1[4], HP2[4], HP3[4];
    split8(hv, HP1, HP2, HP3);
    Frag Ah12, Ah13;
#pragma unroll
    for (int p = 0; p < 4; ++p) {
      Ah12.u[p] = qlo ? HP1[p] : HP2[p];
      Ah13.u[p] = qlo ? HP1[p] : HP3[p];
    }
    // ---- x fragments ----
    unsigned XP1[4], XP2[4], XP3[4];
    split8(cur.v, XP1, XP2, XP3);
    Frag Ax1, Ax2, Ax3;
#pragma unroll
    for (int p = 0; p < 4; ++p) {
      if (IN == 28) {
        Ax1.u[p] = XP1[p]; Ax2.u[p] = XP2[p]; Ax3.u[p] = XP3[p];
      } else {
        Ax1.u[p] = qlo ? XP1[p] : XP2[p];  // [x1|x2]
        Ax2.u[p] = qlo ? XP1[p] : XP3[p];  // [x1|x3]
      }
    }
    // ---- MFMAs ----
    f32x4 acc[4];
#pragma unroll
    for (int g = 0; g < 4; ++g) {
      f32x4 a = {0.f, 0.f, 0.f, 0.f};
      if (IN == 28) {
        a = MFMA(Ax1, BX1[g], a);  // x1W1
        a = MFMA(Ax2, BX1[g], a);  // x2W1
        a = MFMA(Ax3, BX1[g], a);  // x3W1
        a = MFMA(Ax1, BX2[g], a);  // x1W2
        a = MFMA(Ax2, BX2[g], a);  // x2W2
        a = MFMA(Ax1, BX3[g], a);  // x1W3
      } else {
        a = MFMA(Ax1, BX1[g], a);  // x1W1 + x2W1
        a = MFMA(Ax1, BX2[g], a);  // x1W2 + x2W2
        a = MFMA(Ax2, BX3[g], a);  // x1W3 + x3W1
      }
      a = MFMA(Ah12, BH1[g], a);   // h1W1 + h2W1 (+bias b1,b2)
      a = MFMA(Ah12, BH2[g], a);   // h1W2 + h2W2 (+bias b3)
      a = MFMA(Ah13, BH3[g], a);   // h1W3 + h3W1
      acc[g] = a;
    }
    // ---- activations + cell update + stores ----
    float ccs[4] = {cc0, cc1, cc2, cc3};
#pragma unroll
    for (int i = 0; i < 4; ++i) {
      const float zi = acc[0][i], zf = acc[1][i], zg = acc[2][i], zo = acc[3][i];
      const float Ei = __builtin_amdgcn_exp2f(zi * NL2E);
      const float Ef = __builtin_amdgcn_exp2f(zf * NL2E);
      const float Eo = __builtin_amdgcn_exp2f(zo * NL2E);
      const float Eg = __builtin_amdgcn_exp2f(fabsf(zg) * N2L2E);
      const float itg =
          copysignf((1.f - Eg) * __builtin_amdgcn_rcpf((1.f + Ei) * (1.f + Eg)), zg);
      const float cn = ccs[i] * __builtin_amdgcn_rcpf(1.f + Ef) + itg;
      const float Ec = __builtin_amdgcn_exp2f(fabsf(cn) * N2L2E);
      const float hn =
          copysignf((1.f - Ec) * __builtin_amdgcn_rcpf((1.f + Eo) * (1.f + Ec)), cn);
      ccs[i] = cn;
      hbuf[w][4 * q + i][col] = jv ? hn : 1.0f;  // pads stay 1.0 (bias A-slots)
      if (jv) y[yb[i] + (long)t * OCP] = hn;
    }
    cc0 = ccs[0]; cc1 = ccs[1]; cc2 = ccs[2]; cc3 = ccs[3];
  };

  XB xA, xB;
  const int t0 = dir ? T - 1 : 0;
  loadx(xA, t0);
#pragma unroll 1
  for (int s = 0; s < T; s += 2) {
    const int ta = dir ? T - 1 - s : s;
    const int tb = dir ? T - 2 - s : s + 1;
    const int tc = (s + 2 < T) ? (dir ? T - 3 - s : s + 2) : tb;
    step(ta, tb, xA, xB);
    step(tb, tc, xB, xA);
  }
}

extern "C" void kernel_launch(void* const* d_in, const int* in_sizes, int n_in,
                              void* d_out, int out_size, void* d_ws, size_t ws_size,
                              hipStream_t stream) {
  const float* x     = (const float*)d_in[0];
  const float* wih1f = (const float*)d_in[1];
  const float* whh1f = (const float*)d_in[2];
  const float* bih1f = (const float*)d_in[3];
  const float* bhh1f = (const float*)d_in[4];
  const float* wih1b = (const float*)d_in[5];
  const float* whh1b = (const float*)d_in[6];
  const float* bih1b = (const float*)d_in[7];
  const float* bhh1b = (const float*)d_in[8];
  const float* wih2f = (const float*)d_in[9];
  const float* whh2f = (const float*)d_in[10];
  const float* bih2f = (const float*)d_in[11];
  const float* bhh2f = (const float*)d_in[12];
  const float* wih2b = (const float*)d_in[13];
  const float* whh2b = (const float*)d_in[14];
  const float* bih2b = (const float*)d_in[15];
  const float* bhh2b = (const float*)d_in[16];
  const float* wih3  = (const float*)d_in[17];
  const float* whh3  = (const float*)d_in[18];
  const float* bih3  = (const float*)d_in[19];
  const float* bhh3  = (const float*)d_in[20];

  float* y1 = (float*)d_ws;                          // [B, T, 28]
  float* y2 = y1 + (size_t)BATCH * T * 2 * H;        // [B, T, 28]
  float* out = (float*)d_out;                        // [B, T, 14]

  const dim3 blk(256);
  const dim3 grid_bi(BATCH / 64, 2);
  const dim3 grid_uni(BATCH / 64, 1);

  lstm3<13, 28><<<grid_bi, blk, 0, stream>>>(
      x, wih1f, whh1f, bih1f, bhh1f, wih1b, whh1b, bih1b, bhh1b, y1);
  lstm3<28, 28><<<grid_bi, blk, 0, stream>>>(
      y1, wih2f, whh2f, bih2f, bhh2f, wih2b, whh2b, bih2b, bhh2b, y2);
  lstm3<28, 14><<<grid_uni, blk, 0, stream>>>(
      y2, wih3, whh3, bih3, bhh3, wih3, whh3, bih3, bhh3, out);
}